// Round 6
// baseline (191.768 us; speedup 1.0000x reference)
//
#include <hip/hip_runtime.h>
#include <hip/hip_bf16.h>
#include <hip/hip_cooperative_groups.h>
#include <math.h>

namespace cg = cooperative_groups;

#define CIN 256
#define COUT 768   // 3 * OUTC
#define OUTC 256
#define HH 64
#define WW 64
#define HW 4096

typedef unsigned int uint32;
typedef unsigned short ushort16;

using short8 = __attribute__((ext_vector_type(8))) short;
using f32x4  = __attribute__((ext_vector_type(4))) float;

__device__ inline uint32 pkbf2(float a, float b) {
    __hip_bfloat162 h = __float22bfloat162_rn(make_float2(a, b));
    union { __hip_bfloat162 h2; uint32 u; } cv; cv.h2 = h;
    return cv.u;
}
__device__ inline uint32 pkhf2(float a, float b) {
    union { _Float16 h[2]; uint32 u; } cv;
    cv.h[0] = (_Float16)a; cv.h[1] = (_Float16)b;
    return cv.u;
}
__device__ inline float f16lo(uint32 u) {
    union { uint32 u; _Float16 h[2]; } c; c.u = u; return (float)c.h[0];
}
__device__ inline float f16hi(uint32 u) {
    union { uint32 u; _Float16 h[2]; } c; c.u = u; return (float)c.h[1];
}
__device__ inline float dpp_xor1(float x) {
#if __has_builtin(__builtin_amdgcn_update_dpp)
    int i = __builtin_amdgcn_update_dpp(0, __float_as_int(x),
                                        0xB1, 0xF, 0xF, true);
    return __int_as_float(i);
#else
    return __shfl_xor(x, 1, 64);
#endif
}
// async global -> LDS, 16 B per lane (wave-uniform LDS base + lane*16)
__device__ inline void gld16(const void* g, void* l) {
    __builtin_amdgcn_global_load_lds(
        (const __attribute__((address_space(1))) unsigned int*)g,
        (__attribute__((address_space(3))) unsigned int*)l, 16, 0, 0);
}

// attention tile geometry
#define TR 4
#define TC 32
#define HR 8
#define HC 36
#define NPIX (HR*HC)  // 288

// ---------------------------------------------------------------------------
// Single cooperative kernel, 512 blocks x 256 threads, 2 blocks/CU.
// Phase 0: W fp32->bf16; x [n][c][p] fp32 -> xT [n][p][c] bf16 (LDS transpose)
// Phase 1: GEMM qkv = W*xT + b, bf16 MFMA, global_load_lds dbuf staging.
//          tiles 128d x 64p, 3 tiles/block (same n,p0 triple -> B L2-hot)
// Phase 2: 5x5 neighborhood attention (R4 body), 2 tiles/block.
// ---------------------------------------------------------------------------
__global__ __launch_bounds__(256, 2) void fused_kernel(
    const float* __restrict__ x, const float* __restrict__ wq,
    const float* __restrict__ bq, ushort16* __restrict__ xT,
    ushort16* __restrict__ wbf, ushort16* __restrict__ qkv,
    float* __restrict__ out)
{
    __shared__ __align__(16) char smem[36928];

    const int bid = blockIdx.x;
    const int tid = threadIdx.x;

    // ================= Phase 0a: W convert =================
    {
        const int gid = bid * 256 + tid;
        if (gid < (COUT * CIN / 8)) {
            const float* s = wq + (size_t)gid * 8;
            float4 a = *(const float4*)s;
            float4 b = *(const float4*)(s + 4);
            *(uint4*)&wbf[(size_t)gid * 8] =
                make_uint4(pkbf2(a.x, a.y), pkbf2(a.z, a.w),
                           pkbf2(b.x, b.y), pkbf2(b.z, b.w));
        }
    }

    // ================= Phase 0b: x transpose-convert =================
    {
        float (*T)[65] = (float(*)[65])smem;   // 16.6 KB
        const int ty = tid >> 4, tx = tid & 15;
        #pragma unroll 1
        for (int it = 0; it < 2; ++it) {
            const int t  = bid + it * 512;
            const int n  = t >> 8;
            const int c0 = ((t >> 6) & 3) * 64;
            const int p0 = (t & 63) * 64;
            __syncthreads();
            #pragma unroll
            for (int i = 0; i < 4; ++i) {
                float4 v = *(const float4*)&x[((size_t)(n * CIN + c0 + i * 16 + ty)) * HW + p0 + tx * 4];
                T[i * 16 + ty][tx * 4 + 0] = v.x;
                T[i * 16 + ty][tx * 4 + 1] = v.y;
                T[i * 16 + ty][tx * 4 + 2] = v.z;
                T[i * 16 + ty][tx * 4 + 3] = v.w;
            }
            __syncthreads();
            #pragma unroll
            for (int j = 0; j < 2; ++j) {
                const int tt = j * 256 + tid;
                const int pl = tt >> 3, oc = tt & 7;
                uint32 u0 = pkbf2(T[oc * 8 + 0][pl], T[oc * 8 + 1][pl]);
                uint32 u1 = pkbf2(T[oc * 8 + 2][pl], T[oc * 8 + 3][pl]);
                uint32 u2 = pkbf2(T[oc * 8 + 4][pl], T[oc * 8 + 5][pl]);
                uint32 u3 = pkbf2(T[oc * 8 + 6][pl], T[oc * 8 + 7][pl]);
                *(uint4*)&xT[((size_t)n * HW + p0 + pl) * CIN + c0 + oc * 8] =
                    make_uint4(u0, u1, u2, u3);
            }
        }
    }

    cg::this_grid().sync();

    // ================= Phase 1: GEMM =================
    {
        ushort16* As = (ushort16*)smem;          // [2][128*32] = 16 KB
        ushort16* Bs = (ushort16*)smem + 8192;   // [2][64*32]  =  8 KB
        const int lane = tid & 63;
        const int wid  = tid >> 6;
        const int wm = wid >> 1, wn = wid & 1;
        const int lrow = lane & 15;
        const int lk   = (lane >> 4) * 8;
        const int srow = lane >> 2;
        const int skk  = (lane & 3) * 8;

        #pragma unroll 1
        for (int it = 0; it < 3; ++it) {
            const int t   = bid + it * 512;
            const int dt  = t >> 8;
            const int rem = t & 255;
            const int n   = rem >> 6;
            const int pt  = rem & 63;
            const int d0  = dt * 128;
            const int p0  = pt * 64;

            const ushort16* ag = wbf + (size_t)(d0 + wid * 32 + srow) * CIN + skk;
            const ushort16* bg = xT + ((size_t)n * HW + p0 + wid * 16 + srow) * CIN + skk;

            f32x4 acc[4][2];
            #pragma unroll
            for (int i = 0; i < 4; ++i)
                #pragma unroll
                for (int j = 0; j < 2; ++j) acc[i][j] = (f32x4){0.f, 0.f, 0.f, 0.f};

#define STG(buf, ko) do {                                                     \
            gld16(ag + (ko),            As + (buf) * 4096 + (wid * 32) * 32); \
            gld16(ag + (ko) + 16 * CIN, As + (buf) * 4096 + (wid * 32 + 16) * 32); \
            gld16(bg + (ko),            Bs + (buf) * 2048 + (wid * 16) * 32); \
        } while (0)

            __syncthreads();          // LDS free from previous user
            STG(0, 0);
            __syncthreads();          // drains vmcnt -> buf0 ready

            int cur = 0;
            #pragma unroll 1
            for (int kt = 0; kt < 8; ++kt) {
                if (kt < 7) STG(cur ^ 1, (kt + 1) * 32);

                short8 af[4], bf[2];
                #pragma unroll
                for (int fm = 0; fm < 4; ++fm)
                    af[fm] = *(const short8*)(As + cur * 4096 + (wm * 64 + fm * 16 + lrow) * 32 + lk);
                #pragma unroll
                for (int fn = 0; fn < 2; ++fn)
                    bf[fn] = *(const short8*)(Bs + cur * 2048 + (wn * 32 + fn * 16 + lrow) * 32 + lk);
                #pragma unroll
                for (int fm = 0; fm < 4; ++fm)
                    #pragma unroll
                    for (int fn = 0; fn < 2; ++fn)
                        acc[fm][fn] = __builtin_amdgcn_mfma_f32_16x16x32_bf16(
                            af[fm], bf[fn], acc[fm][fn], 0, 0, 0);

                __syncthreads();      // vmcnt (next buf) + lgkm (cur reads)
                cur ^= 1;
            }
#undef STG

            // epilogue: bias + fp16 pack, layout [n][slot][p][dlow]
            const int hi4 = lane >> 4;
            ushort16* qn = qkv + (size_t)n * COUT * HW;
            #pragma unroll
            for (int fm = 0; fm < 4; ++fm) {
                const int D = d0 + wm * 64 + fm * 16 + hi4 * 4;
                const float4 bias = *(const float4*)(&bq[D]);
                const int slot = D >> 5, dlow = D & 31;
                ushort16* qs = qn + (size_t)slot * (HW * 32) + dlow;
                #pragma unroll
                for (int fn = 0; fn < 2; ++fn) {
                    const int p = p0 + wn * 32 + fn * 16 + lrow;
                    f32x4 v = acc[fm][fn];
                    uint32 u0 = pkhf2(v[0] + bias.x, v[1] + bias.y);
                    uint32 u1 = pkhf2(v[2] + bias.z, v[3] + bias.w);
                    *(uint2*)(qs + (size_t)p * 32) = make_uint2(u0, u1);
                }
            }
        }
    }

    cg::this_grid().sync();

    // ================= Phase 2: attention =================
    {
        uint4* Ks = (uint4*)smem;          // 18 KB
        uint4* Vs = Ks + NPIX * 4;         // 18 KB

        const int half = tid & 1;
        const int wc   = (tid >> 1) & 31;
        const int tr   = tid >> 6;

        #pragma unroll 1
        for (int it = 0; it < 2; ++it) {
            const int t    = bid + it * 512;
            const int n    = t >> 8;
            const int head = (t >> 5) & 7;
            const int tl   = t & 31;
            const int h0   = (tl >> 1) * TR;
            const int w0   = (tl & 1) * TC;

            const int h = h0 + tr, w = w0 + wc;
            const int p = h * WW + w;

            const uint4* Kb = (const uint4*)(qkv + ((size_t)(n * 24 + 8 + head)) * HW * 32);
            const uint4* Vb = (const uint4*)(qkv + ((size_t)(n * 24 + 16 + head)) * HW * 32);

            __syncthreads();   // LDS free from previous user

            for (int c = tid; c < 2 * NPIX * 4; c += 256) {
                const int b  = (c >= NPIX * 4);
                const int cc = c - b * NPIX * 4;
                const int pix = cc >> 2, i = cc & 3;
                const int hr = pix / HC, cw = pix - hr * HC;
                const int hh = h0 + hr - 2, ww = w0 + cw - 2;
                if (hh >= 0 && hh < HH && ww >= 0 && ww < WW) {
                    const int pp = hh * WW + ww;
                    const uint4 v = (b ? Vb : Kb)[(size_t)pp * 4 + i];
                    const int unit = (pix * 4 + i) ^ (pix & 7);
                    (b ? Vs : Ks)[unit] = v;
                }
            }

            float qf[16];
            {
                const uint4* Qp = (const uint4*)(qkv + (((size_t)(n * 24 + head)) * HW + p) * 32);
                #pragma unroll
                for (int i = 0; i < 2; ++i) {
                    uint4 u = Qp[half * 2 + i];
                    qf[8*i+0] = f16lo(u.x); qf[8*i+1] = f16hi(u.x);
                    qf[8*i+2] = f16lo(u.y); qf[8*i+3] = f16hi(u.y);
                    qf[8*i+4] = f16lo(u.z); qf[8*i+5] = f16hi(u.z);
                    qf[8*i+6] = f16lo(u.w); qf[8*i+7] = f16hi(u.w);
                }
            }

            __syncthreads();

            float sc[25];
            #pragma unroll
            for (int ky = 0; ky < 5; ++ky) {
                const int hh = h + ky - 2;
                const int hr = tr + ky;
                #pragma unroll
                for (int kx = 0; kx < 5; ++kx) {
                    const int ww = w + kx - 2;
                    float s;
                    if (hh >= 0 && hh < HH && ww >= 0 && ww < WW) {
                        const int pix = hr * HC + (wc + kx);
                        const int u0 = (pix * 4 + half * 2)     ^ (pix & 7);
                        const int u1 = (pix * 4 + half * 2 + 1) ^ (pix & 7);
                        uint4 a = Ks[u0], b = Ks[u1];
                        float tt = 0.f;
                        tt = fmaf(qf[0],  f16lo(a.x), tt); tt = fmaf(qf[1],  f16hi(a.x), tt);
                        tt = fmaf(qf[2],  f16lo(a.y), tt); tt = fmaf(qf[3],  f16hi(a.y), tt);
                        tt = fmaf(qf[4],  f16lo(a.z), tt); tt = fmaf(qf[5],  f16hi(a.z), tt);
                        tt = fmaf(qf[6],  f16lo(a.w), tt); tt = fmaf(qf[7],  f16hi(a.w), tt);
                        tt = fmaf(qf[8],  f16lo(b.x), tt); tt = fmaf(qf[9],  f16hi(b.x), tt);
                        tt = fmaf(qf[10], f16lo(b.y), tt); tt = fmaf(qf[11], f16hi(b.y), tt);
                        tt = fmaf(qf[12], f16lo(b.z), tt); tt = fmaf(qf[13], f16hi(b.z), tt);
                        tt = fmaf(qf[14], f16lo(b.w), tt); tt = fmaf(qf[15], f16hi(b.w), tt);
                        s = tt;
                    } else {
                        s = -1e30f;
                    }
                    sc[ky * 5 + kx] = s;
                }
            }
            #pragma unroll
            for (int k = 0; k < 25; ++k) {
                float o = dpp_xor1(sc[k]);
                sc[k] = (sc[k] <= -1e29f) ? sc[k] : sc[k] + o;
            }

            float m = sc[0];
            #pragma unroll
            for (int k = 1; k < 25; ++k) m = fmaxf(m, sc[k]);
            float sum = 0.f;
            #pragma unroll
            for (int k = 0; k < 25; ++k) {
                float e = __expf(sc[k] - m);
                sc[k] = e;
                sum += e;
            }
            const float inv = 1.f / sum;

            float al[8], ah[8];
            #pragma unroll
            for (int i = 0; i < 8; ++i) { al[i] = 0.f; ah[i] = 0.f; }
            #pragma unroll
            for (int ky = 0; ky < 5; ++ky) {
                const int hh = h + ky - 2;
                if (hh < 0 || hh >= HH) continue;
                const int hr = tr + ky;
                #pragma unroll
                for (int kx = 0; kx < 5; ++kx) {
                    const int ww = w + kx - 2;
                    if (ww < 0 || ww >= WW) continue;
                    const float a = sc[ky * 5 + kx];
                    const int pix = hr * HC + (wc + kx);
                    const int u0 = (pix * 4 + half * 2)     ^ (pix & 7);
                    const int u1 = (pix * 4 + half * 2 + 1) ^ (pix & 7);
                    uint4 xv = Vs[u0], yv = Vs[u1];
                    al[0] = fmaf(a, f16lo(xv.x), al[0]); ah[0] = fmaf(a, f16hi(xv.x), ah[0]);
                    al[1] = fmaf(a, f16lo(xv.y), al[1]); ah[1] = fmaf(a, f16hi(xv.y), ah[1]);
                    al[2] = fmaf(a, f16lo(xv.z), al[2]); ah[2] = fmaf(a, f16hi(xv.z), ah[2]);
                    al[3] = fmaf(a, f16lo(xv.w), al[3]); ah[3] = fmaf(a, f16hi(xv.w), ah[3]);
                    al[4] = fmaf(a, f16lo(yv.x), al[4]); ah[4] = fmaf(a, f16hi(yv.x), ah[4]);
                    al[5] = fmaf(a, f16lo(yv.y), al[5]); ah[5] = fmaf(a, f16hi(yv.y), ah[5]);
                    al[6] = fmaf(a, f16lo(yv.z), al[6]); ah[6] = fmaf(a, f16hi(yv.z), ah[6]);
                    al[7] = fmaf(a, f16lo(yv.w), al[7]); ah[7] = fmaf(a, f16hi(yv.w), ah[7]);
                }
            }

            float* Ob = out + ((size_t)(n * 8 + head) * 32 + half * 16) * HW + p;
            #pragma unroll
            for (int i = 0; i < 8; ++i) {
                Ob[(size_t)(2*i)   * HW] = al[i] * inv;
                Ob[(size_t)(2*i+1) * HW] = ah[i] * inv;
            }
        }
    }
}

// ---------------------------------------------------------------------------
extern "C" void kernel_launch(void* const* d_in, const int* in_sizes, int n_in,
                              void* d_out, int out_size, void* d_ws, size_t ws_size,
                              hipStream_t stream) {
    const float* x  = (const float*)d_in[0];   // (4, 256, 64, 64)
    const float* wq = (const float*)d_in[1];   // (768, 256)
    const float* bq = (const float*)d_in[2];   // (768,)
    float* outp = (float*)d_out;               // (4, 256, 64, 64) fp32

    ushort16* qkv = (ushort16*)d_ws;                          // 25.2 MB fp16 packed
    ushort16* xT  = (ushort16*)((char*)d_ws + (32u << 20));   // 8.4 MB bf16 [n][p][c]
    ushort16* wbf = (ushort16*)((char*)d_ws + (44u << 20));   // 0.4 MB bf16 [d][c]

    void* args[] = { (void*)&x, (void*)&wq, (void*)&bq, (void*)&xT,
                     (void*)&wbf, (void*)&qkv, (void*)&outp };
    hipLaunchCooperativeKernel((void*)fused_kernel, dim3(512), dim3(256),
                               args, 0, stream);
}

// Round 7
// 84.167 us; speedup vs baseline: 2.2784x; 2.2784x over previous
//
#include <hip/hip_runtime.h>
#include <hip/hip_bf16.h>
#include <math.h>

#define CIN 256
#define COUT 768   // 3 * OUTC
#define OUTC 256
#define HH 64
#define WW 64
#define HW 4096

typedef unsigned int uint32;
typedef unsigned short ushort16;

using short8 = __attribute__((ext_vector_type(8))) short;
using f32x4  = __attribute__((ext_vector_type(4))) float;

__device__ inline uint32 pkbf2(float a, float b) {
    __hip_bfloat162 h = __float22bfloat162_rn(make_float2(a, b));
    union { __hip_bfloat162 h2; uint32 u; } cv; cv.h2 = h;
    return cv.u;
}
__device__ inline uint32 pkhf2(float a, float b) {
    union { _Float16 h[2]; uint32 u; } cv;
    cv.h[0] = (_Float16)a; cv.h[1] = (_Float16)b;
    return cv.u;
}
__device__ inline float f16lo(uint32 u) {
    union { uint32 u; _Float16 h[2]; } c; c.u = u; return (float)c.h[0];
}
__device__ inline float f16hi(uint32 u) {
    union { uint32 u; _Float16 h[2]; } c; c.u = u; return (float)c.h[1];
}
__device__ inline float dpp_xor1(float x) {
#if __has_builtin(__builtin_amdgcn_update_dpp)
    int i = __builtin_amdgcn_update_dpp(0, __float_as_int(x),
                                        0xB1, 0xF, 0xF, true);
    return __int_as_float(i);
#else
    return __shfl_xor(x, 1, 64);
#endif
}

// opaque pointer launder: forces the compiler to treat p as unknown each rep
// (prevents CSE of loads/compute across the rep loop; "memory" also kills
// LDS-content assumptions). Rule-17-style liveness anchor.
template <typename T>
__device__ inline T* launder_ptr(T* p) {
    unsigned long long u = (unsigned long long)p;
    asm volatile("" : "+v"(u) :: "memory");
    return (T*)u;
}

// ---------------------------------------------------------------------------
// Kernel 1: QKV projection, bf16 MFMA (R4 body), run `reps` times.
// Output layout: qkv_f16[n][slot=d>>5][p][dlow=d&31]
// ---------------------------------------------------------------------------
#define LDSTR 40   // shorts per LDS row (32 + 8 pad)

__global__ __launch_bounds__(256) void qkv_gemm_kernel(
    const float* __restrict__ x, const float* __restrict__ wq,
    const float* __restrict__ bq, ushort16* __restrict__ qkv, int reps)
{
    __shared__ ushort16 As[128 * LDSTR];  // [d-row][k]
    __shared__ ushort16 Bs[128 * LDSTR];  // [p-col][k]

    const int n   = blockIdx.z;
    const int d0  = blockIdx.y * 128;
    const int p0  = blockIdx.x * 128;
    const int tid = threadIdx.x;
    const int lane = tid & 63;
    const int wid  = tid >> 6;
    const int wm = wid >> 1;
    const int wn = wid & 1;

    const float* xb = x + (size_t)n * CIN * HW;

    const int arow = tid >> 2;
    const int akk  = (tid & 3) * 8;
    const int bkg = (tid >> 6) * 8;
    const int bpg = (tid & 63) * 2;

    ushort16* awr0 = (ushort16*)&As[arow * LDSTR + akk];
    ushort16* awr1 = (ushort16*)&As[(arow + 64) * LDSTR + akk];
    ushort16* bwr0 = (ushort16*)&Bs[bpg * LDSTR + bkg];
    ushort16* bwr1 = (ushort16*)&Bs[(bpg + 1) * LDSTR + bkg];

    const int lrow = lane & 15;
    const int lk   = (lane >> 4) * 8;

    #pragma unroll 1
    for (int rep = 0; rep < reps; ++rep) {
        // laundered per-rep source pointers: compiler must re-load / re-compute
        const float* aptr = launder_ptr(wq) + (size_t)(d0 + arow) * CIN + akk;
        const float* bptr = launder_ptr(xb) + (size_t)bkg * HW + p0 + bpg;

        f32x4 acc[4][4];
        #pragma unroll
        for (int i = 0; i < 4; ++i)
            #pragma unroll
            for (int j = 0; j < 4; ++j) acc[i][j] = (f32x4){0.f, 0.f, 0.f, 0.f};

        float4 a_st[4];
        float2 b_st[8];

        {
            a_st[0] = *(const float4*)(aptr);
            a_st[1] = *(const float4*)(aptr + 4);
            a_st[2] = *(const float4*)(aptr + (size_t)64 * CIN);
            a_st[3] = *(const float4*)(aptr + (size_t)64 * CIN + 4);
            #pragma unroll
            for (int j = 0; j < 8; ++j)
                b_st[j] = *(const float2*)(bptr + (size_t)j * HW);
        }

        #pragma unroll 1
        for (int kt = 0; kt < 8; ++kt) {
            __syncthreads();   // previous MFMA phase (or prev rep) done reading LDS

            {
                uint32 w0 = pkbf2(a_st[0].x, a_st[0].y), w1 = pkbf2(a_st[0].z, a_st[0].w);
                uint32 w2 = pkbf2(a_st[1].x, a_st[1].y), w3 = pkbf2(a_st[1].z, a_st[1].w);
                *(uint4*)awr0 = make_uint4(w0, w1, w2, w3);
                w0 = pkbf2(a_st[2].x, a_st[2].y); w1 = pkbf2(a_st[2].z, a_st[2].w);
                w2 = pkbf2(a_st[3].x, a_st[3].y); w3 = pkbf2(a_st[3].z, a_st[3].w);
                *(uint4*)awr1 = make_uint4(w0, w1, w2, w3);
                uint4 c0, c1;
                c0.x = pkbf2(b_st[0].x, b_st[1].x); c0.y = pkbf2(b_st[2].x, b_st[3].x);
                c0.z = pkbf2(b_st[4].x, b_st[5].x); c0.w = pkbf2(b_st[6].x, b_st[7].x);
                c1.x = pkbf2(b_st[0].y, b_st[1].y); c1.y = pkbf2(b_st[2].y, b_st[3].y);
                c1.z = pkbf2(b_st[4].y, b_st[5].y); c1.w = pkbf2(b_st[6].y, b_st[7].y);
                *(uint4*)bwr0 = c0;
                *(uint4*)bwr1 = c1;
            }

            if (kt < 7) {
                const int ko = (kt + 1) * 32;
                a_st[0] = *(const float4*)(aptr + ko);
                a_st[1] = *(const float4*)(aptr + ko + 4);
                a_st[2] = *(const float4*)(aptr + (size_t)64 * CIN + ko);
                a_st[3] = *(const float4*)(aptr + (size_t)64 * CIN + ko + 4);
                #pragma unroll
                for (int j = 0; j < 8; ++j)
                    b_st[j] = *(const float2*)(bptr + (size_t)(ko + j) * HW);
            }

            __syncthreads();   // LDS tile visible

            short8 af[4], bf[4];
            #pragma unroll
            for (int fm = 0; fm < 4; ++fm)
                af[fm] = *(const short8*)&As[(wm * 64 + fm * 16 + lrow) * LDSTR + lk];
            #pragma unroll
            for (int fn = 0; fn < 4; ++fn)
                bf[fn] = *(const short8*)&Bs[(wn * 64 + fn * 16 + lrow) * LDSTR + lk];
            #pragma unroll
            for (int fm = 0; fm < 4; ++fm)
                #pragma unroll
                for (int fn = 0; fn < 4; ++fn)
                    acc[fm][fn] = __builtin_amdgcn_mfma_f32_16x16x32_bf16(
                        af[fm], bf[fn], acc[fm][fn], 0, 0, 0);
        }

        // epilogue: bias + cvt fp16 + store packed [n][slot][p][dlow]
        const int hi4 = lane >> 4;
        ushort16* qn = qkv + (size_t)n * COUT * HW;
        #pragma unroll
        for (int fm = 0; fm < 4; ++fm) {
            const int D = d0 + wm * 64 + fm * 16 + hi4 * 4;
            const float4 bias = *(const float4*)(&bq[D]);
            const int slot = D >> 5, dlow = D & 31;
            ushort16* qs = qn + (size_t)slot * (HW * 32) + dlow;
            #pragma unroll
            for (int fn = 0; fn < 4; ++fn) {
                const int p = p0 + wn * 64 + fn * 16 + lrow;
                f32x4 v = acc[fm][fn];
                uint32 u0 = pkhf2(v[0] + bias.x, v[1] + bias.y);
                uint32 u1 = pkhf2(v[2] + bias.z, v[3] + bias.w);
                *(uint2*)(qs + (size_t)p * 32) = make_uint2(u0, u1);
            }
        }
    }
}

// ---------------------------------------------------------------------------
// Kernel 2: 5x5 neighborhood attention (R4 body), run `reps` times.
// ---------------------------------------------------------------------------
#define TR 4
#define TC 32
#define HR 8
#define HC 36
#define NPIX (HR*HC)  // 288

__global__ __launch_bounds__(256) void attn_kernel(
    const ushort16* __restrict__ qkv, float* __restrict__ out, int reps)
{
    __shared__ uint4 Ks[NPIX * 4];   // 18 KB
    __shared__ uint4 Vs[NPIX * 4];   // 18 KB

    const int n    = blockIdx.z;
    const int head = blockIdx.y;
    const int ht = blockIdx.x >> 1;
    const int wt = blockIdx.x & 1;
    const int h0 = ht * TR;
    const int w0 = wt * TC;

    const int tid  = threadIdx.x;
    const int half = tid & 1;
    const int wc   = (tid >> 1) & 31;
    const int tr   = tid >> 6;

    const int h = h0 + tr, w = w0 + wc;
    const int p = h * WW + w;

    #pragma unroll 1
    for (int rep = 0; rep < reps; ++rep) {
        const ushort16* qv = launder_ptr(qkv);
        const uint4* Kb = (const uint4*)(qv + ((size_t)(n * 24 + 8 + head)) * HW * 32);
        const uint4* Vb = (const uint4*)(qv + ((size_t)(n * 24 + 16 + head)) * HW * 32);

        __syncthreads();   // prev rep's readers done before restaging

        for (int c = tid; c < 2 * NPIX * 4; c += 256) {
            const int b  = (c >= NPIX * 4);
            const int cc = c - b * NPIX * 4;
            const int pix = cc >> 2, i = cc & 3;
            const int hr = pix / HC, cw = pix - hr * HC;
            const int hh = h0 + hr - 2, ww = w0 + cw - 2;
            if (hh >= 0 && hh < HH && ww >= 0 && ww < WW) {
                const int pp = hh * WW + ww;
                const uint4 v = (b ? Vb : Kb)[(size_t)pp * 4 + i];
                const int unit = (pix * 4 + i) ^ (pix & 7);
                (b ? Vs : Ks)[unit] = v;
            }
        }

        float qf[16];
        {
            const uint4* Qp = (const uint4*)(qv + (((size_t)(n * 24 + head)) * HW + p) * 32);
            #pragma unroll
            for (int i = 0; i < 2; ++i) {
                uint4 u = Qp[half * 2 + i];
                qf[8*i+0] = f16lo(u.x); qf[8*i+1] = f16hi(u.x);
                qf[8*i+2] = f16lo(u.y); qf[8*i+3] = f16hi(u.y);
                qf[8*i+4] = f16lo(u.z); qf[8*i+5] = f16hi(u.z);
                qf[8*i+6] = f16lo(u.w); qf[8*i+7] = f16hi(u.w);
            }
        }

        __syncthreads();

        float sc[25];
        #pragma unroll
        for (int ky = 0; ky < 5; ++ky) {
            const int hh = h + ky - 2;
            const int hr = tr + ky;
            #pragma unroll
            for (int kx = 0; kx < 5; ++kx) {
                const int ww = w + kx - 2;
                float s;
                if (hh >= 0 && hh < HH && ww >= 0 && ww < WW) {
                    const int pix = hr * HC + (wc + kx);
                    const int u0 = (pix * 4 + half * 2)     ^ (pix & 7);
                    const int u1 = (pix * 4 + half * 2 + 1) ^ (pix & 7);
                    uint4 a = Ks[u0], b = Ks[u1];
                    float t = 0.f;
                    t = fmaf(qf[0],  f16lo(a.x), t); t = fmaf(qf[1],  f16hi(a.x), t);
                    t = fmaf(qf[2],  f16lo(a.y), t); t = fmaf(qf[3],  f16hi(a.y), t);
                    t = fmaf(qf[4],  f16lo(a.z), t); t = fmaf(qf[5],  f16hi(a.z), t);
                    t = fmaf(qf[6],  f16lo(a.w), t); t = fmaf(qf[7],  f16hi(a.w), t);
                    t = fmaf(qf[8],  f16lo(b.x), t); t = fmaf(qf[9],  f16hi(b.x), t);
                    t = fmaf(qf[10], f16lo(b.y), t); t = fmaf(qf[11], f16hi(b.y), t);
                    t = fmaf(qf[12], f16lo(b.z), t); t = fmaf(qf[13], f16hi(b.z), t);
                    t = fmaf(qf[14], f16lo(b.w), t); t = fmaf(qf[15], f16hi(b.w), t);
                    s = t;
                } else {
                    s = -1e30f;
                }
                sc[ky * 5 + kx] = s;
            }
        }
        #pragma unroll
        for (int k = 0; k < 25; ++k) {
            float o = dpp_xor1(sc[k]);
            sc[k] = (sc[k] <= -1e29f) ? sc[k] : sc[k] + o;
        }

        float m = sc[0];
        #pragma unroll
        for (int k = 1; k < 25; ++k) m = fmaxf(m, sc[k]);
        float sum = 0.f;
        #pragma unroll
        for (int k = 0; k < 25; ++k) {
            float e = __expf(sc[k] - m);
            sc[k] = e;
            sum += e;
        }
        const float inv = 1.f / sum;

        float al[8], ah[8];
        #pragma unroll
        for (int i = 0; i < 8; ++i) { al[i] = 0.f; ah[i] = 0.f; }
        #pragma unroll
        for (int ky = 0; ky < 5; ++ky) {
            const int hh = h + ky - 2;
            if (hh < 0 || hh >= HH) continue;
            const int hr = tr + ky;
            #pragma unroll
            for (int kx = 0; kx < 5; ++kx) {
                const int ww = w + kx - 2;
                if (ww < 0 || ww >= WW) continue;
                const float a = sc[ky * 5 + kx];
                const int pix = hr * HC + (wc + kx);
                const int u0 = (pix * 4 + half * 2)     ^ (pix & 7);
                const int u1 = (pix * 4 + half * 2 + 1) ^ (pix & 7);
                uint4 xv = Vs[u0], yv = Vs[u1];
                al[0] = fmaf(a, f16lo(xv.x), al[0]); ah[0] = fmaf(a, f16hi(xv.x), ah[0]);
                al[1] = fmaf(a, f16lo(xv.y), al[1]); ah[1] = fmaf(a, f16hi(xv.y), ah[1]);
                al[2] = fmaf(a, f16lo(xv.z), al[2]); ah[2] = fmaf(a, f16hi(xv.z), ah[2]);
                al[3] = fmaf(a, f16lo(xv.w), al[3]); ah[3] = fmaf(a, f16hi(xv.w), ah[3]);
                al[4] = fmaf(a, f16lo(yv.x), al[4]); ah[4] = fmaf(a, f16hi(yv.x), ah[4]);
                al[5] = fmaf(a, f16lo(yv.y), al[5]); ah[5] = fmaf(a, f16hi(yv.y), ah[5]);
                al[6] = fmaf(a, f16lo(yv.z), al[6]); ah[6] = fmaf(a, f16hi(yv.z), ah[6]);
                al[7] = fmaf(a, f16lo(yv.w), al[7]); ah[7] = fmaf(a, f16hi(yv.w), ah[7]);
            }
        }

        float* Ob = out + ((size_t)(n * 8 + head) * 32 + half * 16) * HW + p;
        #pragma unroll
        for (int i = 0; i < 8; ++i) {
            Ob[(size_t)(2*i)   * HW] = al[i] * inv;
            Ob[(size_t)(2*i+1) * HW] = ah[i] * inv;
        }
    }
}

// ---------------------------------------------------------------------------
extern "C" void kernel_launch(void* const* d_in, const int* in_sizes, int n_in,
                              void* d_out, int out_size, void* d_ws, size_t ws_size,
                              hipStream_t stream) {
    const float* x  = (const float*)d_in[0];   // (4, 256, 64, 64)
    const float* wq = (const float*)d_in[1];   // (768, 256)
    const float* bq = (const float*)d_in[2];   // (768,)
    float* out = (float*)d_out;                // (4, 256, 64, 64) fp32
    ushort16* qkv = (ushort16*)d_ws;           // fp16 [4][24][4096][32] = 25 MB

    // INSTRUMENTATION ROUND: each kernel body runs twice (idempotent stores,
    // laundered pointers) so per-kernel duration = (total - 45.8us) and the
    // doubled kernel surfaces in rocprof top-5 with full counters.
    dim3 g1(HW / 128, COUT / 128, 4);          // (32, 6, 4)
    qkv_gemm_kernel<<<g1, 256, 0, stream>>>(x, wq, bq, qkv, 2);

    dim3 g2(32, 8, 4);
    attn_kernel<<<g2, 256, 0, stream>>>(qkv, out, 2);
}

// Round 8
// 50.539 us; speedup vs baseline: 3.7945x; 1.6654x over previous
//
#include <hip/hip_runtime.h>
#include <hip/hip_bf16.h>
#include <math.h>

#define CIN 256
#define COUT 768   // 3 * OUTC
#define OUTC 256
#define HH 64
#define WW 64
#define HW 4096

typedef unsigned int uint32;
typedef unsigned short ushort16;

using short8 = __attribute__((ext_vector_type(8))) short;
using f32x4  = __attribute__((ext_vector_type(4))) float;

__device__ inline uint32 pkbf2(float a, float b) {
    __hip_bfloat162 h = __float22bfloat162_rn(make_float2(a, b));
    union { __hip_bfloat162 h2; uint32 u; } cv; cv.h2 = h;
    return cv.u;
}
__device__ inline uint32 pkhf2(float a, float b) {
    union { _Float16 h[2]; uint32 u; } cv;
    cv.h[0] = (_Float16)a; cv.h[1] = (_Float16)b;
    return cv.u;
}
__device__ inline float f16lo(uint32 u) {
    union { uint32 u; _Float16 h[2]; } c; c.u = u; return (float)c.h[0];
}
__device__ inline float f16hi(uint32 u) {
    union { uint32 u; _Float16 h[2]; } c; c.u = u; return (float)c.h[1];
}
__device__ inline float dpp_xor1(float x) {
#if __has_builtin(__builtin_amdgcn_update_dpp)
    int i = __builtin_amdgcn_update_dpp(0, __float_as_int(x),
                                        0xB1, 0xF, 0xF, true);
    return __int_as_float(i);
#else
    return __shfl_xor(x, 1, 64);
#endif
}

// ---------------------------------------------------------------------------
// Kernel 1 (v3): QKV projection, bf16 MFMA.
// Tile 128d x 64p (was 128x128): 1536 blocks = 6 blocks/CU = 24 waves/CU for
// latency hiding (R7 counters: all pipes <20% busy -> latency-bound).
// LDS XOR-unit swizzle (16B units): A[(r*4+c)^(r&7)], B[(p*4+c)^((p>>1)&7)]
// -> <=2 lanes/bank on staging writes AND ds_read_b128 fragment reads.
// Output: qkv_f16[n][slot=d>>5][p][dlow=d&31]
// ---------------------------------------------------------------------------
__global__ __launch_bounds__(256) void qkv_gemm_kernel(
    const float* __restrict__ x, const float* __restrict__ wq,
    const float* __restrict__ bq, ushort16* __restrict__ qkv)
{
    __shared__ uint4 As[512];   // 128 d-rows x 4 k-chunks (16B = 8 bf16 k's)
    __shared__ uint4 Bs[256];   // 64 p-rows x 4 k-chunks

    const int n   = blockIdx.z;
    const int d0  = blockIdx.y * 128;
    const int p0  = blockIdx.x * 64;
    const int tid = threadIdx.x;
    const int lane = tid & 63;
    const int wid  = tid >> 6;
    const int wm = wid >> 1;     // d-half (0..1)
    const int wn = wid & 1;      // p-half (0..1)

    // A staging: thread -> row ar (2 threads/row), 16 consecutive k each
    const int ar = tid >> 1;
    const int ac0 = (tid & 1) * 2;            // chunk base (0 or 2)
    const float* aptr = wq + (size_t)(d0 + ar) * CIN + ac0 * 8;
    // B staging: thread -> p-pair pp, 4 consecutive k
    const int pp = (tid & 31) * 2;
    const int kq = (tid >> 5) * 4;            // 0,4,...,28
    const int bchunk = kq >> 3;
    const int bsub   = (kq >> 2) & 1;
    const float* bptr = x + (size_t)n * CIN * HW + (size_t)kq * HW + p0 + pp;

    const int lrow = lane & 15;
    const int kc   = lane >> 4;               // fragment k-chunk 0..3

    f32x4 acc[4][2];
    #pragma unroll
    for (int i = 0; i < 4; ++i)
        #pragma unroll
        for (int j = 0; j < 2; ++j) acc[i][j] = (f32x4){0.f, 0.f, 0.f, 0.f};

    float4 a_st[4];
    float2 b_st[4];

    // prologue: kt = 0 loads
    {
        a_st[0] = *(const float4*)(aptr);
        a_st[1] = *(const float4*)(aptr + 4);
        a_st[2] = *(const float4*)(aptr + 8);
        a_st[3] = *(const float4*)(aptr + 12);
        #pragma unroll
        for (int j = 0; j < 4; ++j)
            b_st[j] = *(const float2*)(bptr + (size_t)j * HW);
    }

    const int au0 = (ar * 4 + ac0)     ^ (ar & 7);
    const int au1 = (ar * 4 + ac0 + 1) ^ (ar & 7);
    const int bx  = (pp >> 1) & 7;            // same for pp and pp+1
    const int bu0 = (pp * 4 + bchunk)       ^ bx;
    const int bu1 = ((pp + 1) * 4 + bchunk) ^ bx;

    #pragma unroll 1
    for (int kt = 0; kt < 8; ++kt) {
        __syncthreads();   // previous MFMA phase done reading LDS

        // convert + swizzled LDS write
        As[au0] = make_uint4(pkbf2(a_st[0].x, a_st[0].y), pkbf2(a_st[0].z, a_st[0].w),
                             pkbf2(a_st[1].x, a_st[1].y), pkbf2(a_st[1].z, a_st[1].w));
        As[au1] = make_uint4(pkbf2(a_st[2].x, a_st[2].y), pkbf2(a_st[2].z, a_st[2].w),
                             pkbf2(a_st[3].x, a_st[3].y), pkbf2(a_st[3].z, a_st[3].w));
        {
            uint2 v0 = make_uint2(pkbf2(b_st[0].x, b_st[1].x), pkbf2(b_st[2].x, b_st[3].x));
            uint2 v1 = make_uint2(pkbf2(b_st[0].y, b_st[1].y), pkbf2(b_st[2].y, b_st[3].y));
            ((uint2*)&Bs[bu0])[bsub] = v0;
            ((uint2*)&Bs[bu1])[bsub] = v1;
        }

        // prefetch next K-tile while MFMA runs
        if (kt < 7) {
            const int ko = (kt + 1) * 32;
            a_st[0] = *(const float4*)(aptr + ko);
            a_st[1] = *(const float4*)(aptr + ko + 4);
            a_st[2] = *(const float4*)(aptr + ko + 8);
            a_st[3] = *(const float4*)(aptr + ko + 12);
            #pragma unroll
            for (int j = 0; j < 4; ++j)
                b_st[j] = *(const float2*)(bptr + (size_t)(ko + j) * HW);
        }

        __syncthreads();   // LDS tile visible

        short8 af[4], bf[2];
        #pragma unroll
        for (int fm = 0; fm < 4; ++fm) {
            const int r = wm * 64 + fm * 16 + lrow;
            af[fm] = *(const short8*)&As[(r * 4 + kc) ^ (r & 7)];
        }
        #pragma unroll
        for (int fn = 0; fn < 2; ++fn) {
            const int p = wn * 32 + fn * 16 + lrow;
            bf[fn] = *(const short8*)&Bs[(p * 4 + kc) ^ ((p >> 1) & 7)];
        }
        #pragma unroll
        for (int fm = 0; fm < 4; ++fm)
            #pragma unroll
            for (int fn = 0; fn < 2; ++fn)
                acc[fm][fn] = __builtin_amdgcn_mfma_f32_16x16x32_bf16(
                    af[fm], bf[fn], acc[fm][fn], 0, 0, 0);
    }

    // epilogue: bias + cvt fp16 + store packed [n][slot][p][dlow]
    const int hi4 = lane >> 4;
    ushort16* qn = qkv + (size_t)n * COUT * HW;
    #pragma unroll
    for (int fm = 0; fm < 4; ++fm) {
        const int D = d0 + wm * 64 + fm * 16 + hi4 * 4;
        const float4 bias = *(const float4*)(&bq[D]);
        const int slot = D >> 5, dlow = D & 31;
        ushort16* qs = qn + (size_t)slot * (HW * 32) + dlow;
        #pragma unroll
        for (int fn = 0; fn < 2; ++fn) {
            const int p = p0 + wn * 32 + fn * 16 + lrow;
            f32x4 v = acc[fm][fn];
            uint32 u0 = pkhf2(v[0] + bias.x, v[1] + bias.y);
            uint32 u1 = pkhf2(v[2] + bias.z, v[3] + bias.w);
            *(uint2*)(qs + (size_t)p * 32) = make_uint2(u0, u1);
        }
    }
}

// ---------------------------------------------------------------------------
// Kernel 2: 5x5 neighborhood attention (UNCHANGED R4 body).
// ---------------------------------------------------------------------------
#define TR 4
#define TC 32
#define HR 8
#define HC 36
#define NPIX (HR*HC)  // 288

__global__ __launch_bounds__(256) void attn_kernel(
    const ushort16* __restrict__ qkv, float* __restrict__ out)
{
    __shared__ uint4 Ks[NPIX * 4];   // 18 KB
    __shared__ uint4 Vs[NPIX * 4];   // 18 KB

    const int n    = blockIdx.z;
    const int head = blockIdx.y;
    const int ht = blockIdx.x >> 1;
    const int wt = blockIdx.x & 1;
    const int h0 = ht * TR;
    const int w0 = wt * TC;

    const int tid  = threadIdx.x;
    const int half = tid & 1;
    const int wc   = (tid >> 1) & 31;
    const int tr   = tid >> 6;

    const int h = h0 + tr, w = w0 + wc;
    const int p = h * WW + w;

    const uint4* Kb = (const uint4*)(qkv + ((size_t)(n * 24 + 8 + head)) * HW * 32);
    const uint4* Vb = (const uint4*)(qkv + ((size_t)(n * 24 + 16 + head)) * HW * 32);

    for (int c = tid; c < 2 * NPIX * 4; c += 256) {
        const int b  = (c >= NPIX * 4);
        const int cc = c - b * NPIX * 4;
        const int pix = cc >> 2, i = cc & 3;
        const int hr = pix / HC, cw = pix - hr * HC;
        const int hh = h0 + hr - 2, ww = w0 + cw - 2;
        if (hh >= 0 && hh < HH && ww >= 0 && ww < WW) {
            const int pp = hh * WW + ww;
            const uint4 v = (b ? Vb : Kb)[(size_t)pp * 4 + i];
            const int unit = (pix * 4 + i) ^ (pix & 7);
            (b ? Vs : Ks)[unit] = v;
        }
    }

    float qf[16];
    {
        const uint4* Qp = (const uint4*)(qkv + (((size_t)(n * 24 + head)) * HW + p) * 32);
        #pragma unroll
        for (int i = 0; i < 2; ++i) {
            uint4 u = Qp[half * 2 + i];
            qf[8*i+0] = f16lo(u.x); qf[8*i+1] = f16hi(u.x);
            qf[8*i+2] = f16lo(u.y); qf[8*i+3] = f16hi(u.y);
            qf[8*i+4] = f16lo(u.z); qf[8*i+5] = f16hi(u.z);
            qf[8*i+6] = f16lo(u.w); qf[8*i+7] = f16hi(u.w);
        }
    }

    __syncthreads();

    float sc[25];
    #pragma unroll
    for (int ky = 0; ky < 5; ++ky) {
        const int hh = h + ky - 2;
        const int hr = tr + ky;
        #pragma unroll
        for (int kx = 0; kx < 5; ++kx) {
            const int ww = w + kx - 2;
            float s;
            if (hh >= 0 && hh < HH && ww >= 0 && ww < WW) {
                const int pix = hr * HC + (wc + kx);
                const int u0 = (pix * 4 + half * 2)     ^ (pix & 7);
                const int u1 = (pix * 4 + half * 2 + 1) ^ (pix & 7);
                uint4 a = Ks[u0], b = Ks[u1];
                float t = 0.f;
                t = fmaf(qf[0],  f16lo(a.x), t); t = fmaf(qf[1],  f16hi(a.x), t);
                t = fmaf(qf[2],  f16lo(a.y), t); t = fmaf(qf[3],  f16hi(a.y), t);
                t = fmaf(qf[4],  f16lo(a.z), t); t = fmaf(qf[5],  f16hi(a.z), t);
                t = fmaf(qf[6],  f16lo(a.w), t); t = fmaf(qf[7],  f16hi(a.w), t);
                t = fmaf(qf[8],  f16lo(b.x), t); t = fmaf(qf[9],  f16hi(b.x), t);
                t = fmaf(qf[10], f16lo(b.y), t); t = fmaf(qf[11], f16hi(b.y), t);
                t = fmaf(qf[12], f16lo(b.z), t); t = fmaf(qf[13], f16hi(b.z), t);
                t = fmaf(qf[14], f16lo(b.w), t); t = fmaf(qf[15], f16hi(b.w), t);
                s = t;
            } else {
                s = -1e30f;
            }
            sc[ky * 5 + kx] = s;
        }
    }
    #pragma unroll
    for (int k = 0; k < 25; ++k) {
        float o = dpp_xor1(sc[k]);
        sc[k] = (sc[k] <= -1e29f) ? sc[k] : sc[k] + o;
    }

    float m = sc[0];
    #pragma unroll
    for (int k = 1; k < 25; ++k) m = fmaxf(m, sc[k]);
    float sum = 0.f;
    #pragma unroll
    for (int k = 0; k < 25; ++k) {
        float e = __expf(sc[k] - m);
        sc[k] = e;
        sum += e;
    }
    const float inv = 1.f / sum;

    float al[8], ah[8];
    #pragma unroll
    for (int i = 0; i < 8; ++i) { al[i] = 0.f; ah[i] = 0.f; }
    #pragma unroll
    for (int ky = 0; ky < 5; ++ky) {
        const int hh = h + ky - 2;
        if (hh < 0 || hh >= HH) continue;
        const int hr = tr + ky;
        #pragma unroll
        for (int kx = 0; kx < 5; ++kx) {
            const int ww = w + kx - 2;
            if (ww < 0 || ww >= WW) continue;
            const float a = sc[ky * 5 + kx];
            const int pix = hr * HC + (wc + kx);
            const int u0 = (pix * 4 + half * 2)     ^ (pix & 7);
            const int u1 = (pix * 4 + half * 2 + 1) ^ (pix & 7);
            uint4 xv = Vs[u0], yv = Vs[u1];
            al[0] = fmaf(a, f16lo(xv.x), al[0]); ah[0] = fmaf(a, f16hi(xv.x), ah[0]);
            al[1] = fmaf(a, f16lo(xv.y), al[1]); ah[1] = fmaf(a, f16hi(xv.y), ah[1]);
            al[2] = fmaf(a, f16lo(xv.z), al[2]); ah[2] = fmaf(a, f16hi(xv.z), ah[2]);
            al[3] = fmaf(a, f16lo(xv.w), al[3]); ah[3] = fmaf(a, f16hi(xv.w), ah[3]);
            al[4] = fmaf(a, f16lo(yv.x), al[4]); ah[4] = fmaf(a, f16hi(yv.x), ah[4]);
            al[5] = fmaf(a, f16lo(yv.y), al[5]); ah[5] = fmaf(a, f16hi(yv.y), ah[5]);
            al[6] = fmaf(a, f16lo(yv.z), al[6]); ah[6] = fmaf(a, f16hi(yv.z), ah[6]);
            al[7] = fmaf(a, f16lo(yv.w), al[7]); ah[7] = fmaf(a, f16hi(yv.w), ah[7]);
        }
    }

    float* Ob = out + ((size_t)(n * 8 + head) * 32 + half * 16) * HW + p;
    #pragma unroll
    for (int i = 0; i < 8; ++i) {
        Ob[(size_t)(2*i)   * HW] = al[i] * inv;
        Ob[(size_t)(2*i+1) * HW] = ah[i] * inv;
    }
}

// ---------------------------------------------------------------------------
extern "C" void kernel_launch(void* const* d_in, const int* in_sizes, int n_in,
                              void* d_out, int out_size, void* d_ws, size_t ws_size,
                              hipStream_t stream) {
    const float* x  = (const float*)d_in[0];   // (4, 256, 64, 64)
    const float* wq = (const float*)d_in[1];   // (768, 256)
    const float* bq = (const float*)d_in[2];   // (768,)
    float* out = (float*)d_out;                // (4, 256, 64, 64) fp32
    ushort16* qkv = (ushort16*)d_ws;           // fp16 [4][24][4096][32] = 25 MB

    dim3 g1(HW / 64, COUT / 128, 4);           // (64, 6, 4) = 1536 blocks
    qkv_gemm_kernel<<<g1, 256, 0, stream>>>(x, wq, bq, qkv);

    dim3 g2(32, 8, 4);
    attn_kernel<<<g2, 256, 0, stream>>>(qkv, out);
}